// Round 15
// baseline (42.876 us; speedup 1.0000x reference)
//
#include <hip/hip_runtime.h>

// Problem constants (match reference)
#define NB 32768
#define ND 512
#define NK 10

#define LEFTB (-10.0f)
#define RIGHTB (10.0f)
#define ROWS 8
#define NBLK 512                      // blocks of 1024 threads; 2 blocks/CU
#define SWEEPS (NB / (NBLK * 16))     // = 4 (16 rows per block per sweep)

// DPP row_shr:N add (VALU-only partial reduction within 16-lane rows).
__device__ __forceinline__ float dpp_row_reduce16(float v) {
    v += __int_as_float(__builtin_amdgcn_update_dpp(
        0, __float_as_int(v), 0x111, 0xF, 0xF, true));  // row_shr:1
    v += __int_as_float(__builtin_amdgcn_update_dpp(
        0, __float_as_int(v), 0x112, 0xF, 0xF, true));  // row_shr:2
    v += __int_as_float(__builtin_amdgcn_update_dpp(
        0, __float_as_int(v), 0x114, 0xF, 0xF, true));  // row_shr:4
    v += __int_as_float(__builtin_amdgcn_update_dpp(
        0, __float_as_int(v), 0x118, 0xF, 0xF, true));  // row_shr:8
    return v;
}

// ---------------------------------------------------------------------------
// Single fused kernel. 1024 threads/block (feature = t&511, row-half = t>>9),
// 512 blocks -> 2 blocks/CU = 32 waves/CU; VGPR capped at 64.
//
// Prologue (replaces the separate precompute kernel): table build is SPLIT
// between the halves — hf=0 waves do the width-softmax -> cw knots, hf=1
// waves do the height-softmax -> ch knots + softplus derivatives. ~1 us/CU,
// overlapped with sweep-0 X loads issued beforehand. (r10's fusion failed at
// 9 redundant builds/CU; this is 1 split build across 2 blocks/CU.)
//
// Main loop / epilogue: byte-identical to round 14 (batched body, barrier-
// free sweeps, DPP reduce in log2 units, in-kernel logdet finish).
// ---------------------------------------------------------------------------
__global__ __launch_bounds__(1024, 8) void rqs_all(const float* __restrict__ X,
                                                   const float* __restrict__ uw,
                                                   const float* __restrict__ uh,
                                                   const float* __restrict__ ud,
                                                   float* __restrict__ Y,
                                                   float* __restrict__ logdet) {
    const int t = threadIdx.x;
    const int fl = t & (ND - 1);   // feature
    const int hf = t >> 9;         // row-half 0/1

    __shared__ float2 sCWCH[NK + 1][ND];  // 45056 B  {cw_k, ch_k}
    __shared__ float sDD[NK + 1][ND];     // 22528 B  d_k
    __shared__ float sPart[SWEEPS * 16][32] __attribute__((aligned(16)));  // 8192 B
    // total 75776 B -> 2 blocks/CU
    float* sCWf = (float*)sCWCH;          // component view: (k*ND+fl)*2 + comp

    // issue sweep-0 X loads FIRST (independent of the table build)
    float xs[ROWS];
    {
        const int rb = blockIdx.x * 16 + hf * ROWS;
#pragma unroll
        for (int i = 0; i < ROWS; ++i)
            xs[i] = __builtin_nontemporal_load(&X[(rb + i) * ND + fl]);
    }

    // ---- split table build ----
    {
        const float* up = (hf == 0) ? uw : uh;   // wave-uniform select
        float u[NK];
        float m = -1e30f;
#pragma unroll
        for (int k = 0; k < NK; ++k) { u[k] = up[fl * NK + k]; m = fmaxf(m, u[k]); }
        float s = 0.0f;
#pragma unroll
        for (int k = 0; k < NK; ++k) { u[k] = expf(u[k] - m); s += u[k]; }
        float inv = 1.0f / s;
        sCWf[(0 * ND + fl) * 2 + hf] = LEFTB;
        float c = 0.0f;
#pragma unroll
        for (int k = 0; k < NK; ++k) {
            c += 1e-3f + (1.0f - 1e-3f * NK) * (u[k] * inv);
            float knot = (k == NK - 1) ? RIGHTB
                                       : fmaf(RIGHTB - LEFTB, c, LEFTB);
            sCWf[((k + 1) * ND + fl) * 2 + hf] = knot;
        }
        if (hf == 1) {
            // derivatives: boundary pads are exactly 1.0
            sDD[0][fl] = 1.0f;
            sDD[NK][fl] = 1.0f;
#pragma unroll
            for (int k = 1; k < NK; ++k) {
                float v = ud[fl * (NK - 1) + (k - 1)];
                sDD[k][fl] = 1e-3f + fmaxf(v, 0.0f) + log1pf(expf(-fabsf(v)));
            }
        }
    }
    __syncthreads();

    // register copy of the internal knots for the bin search
    float e[9];
#pragma unroll
    for (int j = 0; j < 9; ++j) e[j] = sCWCH[j + 1][fl].x;

    for (int it = 0; it < SWEEPS; ++it) {
        const int rb = blockIdx.x * 16 + it * (NBLK * 16) + hf * ROWS;

        // prefetch next sweep's X during this sweep's compute
        float xn[ROWS];
        if (it + 1 < SWEEPS) {
            const int rn = rb + NBLK * 16;
#pragma unroll
            for (int i = 0; i < ROWS; ++i)
                xn[i] = __builtin_nontemporal_load(&X[(rn + i) * ND + fl]);
        }

        float ys[ROWS], ls[ROWS];
#pragma unroll
        for (int i = 0; i < ROWS; ++i) {
            float x = xs[i];

            // bin search on raw x: saturates to 0 / 9 outside, same as clamp
            int idx = 0;
#pragma unroll
            for (int j = 0; j < 9; ++j) idx += (x >= e[j]) ? 1 : 0;

            float2 c0 = sCWCH[idx][fl];      // {cw_k,   ch_k}
            float2 c1 = sCWCH[idx + 1][fl];  // {cw_k+1, ch_k+1}
            float dk = sDD[idx][fl];
            float dk1 = sDD[idx + 1][fl];

            float w = c1.x - c0.x;
            float rw = __builtin_amdgcn_rcpf(w);   // w >= 0.02 always
            float h = c1.y - c0.y;
            float delta = h * rw;

            float theta = (x - c0.x) * rw;
            float omt = 1.0f - theta;
            float t1m = theta * omt;
            float th2 = theta * theta;

            float num = h * fmaf(delta, th2, dk * t1m);
            float den = fmaf(fmaf(-2.0f, delta, dk + dk1), t1m, delta);
            float rden = __builtin_amdgcn_rcpf(den);  // den > 0 inside
            float y = fmaf(num, rden, c0.y);

            float dnum = delta * delta *
                         (fmaf(dk1, th2, 2.0f * delta * t1m) + dk * omt * omt);
            float lad2 = __log2f(dnum * rden * rden);  // log2; ln2 at epilogue

            bool inside = fabsf(x) <= RIGHTB;          // abs = free src modifier
            ys[i] = inside ? y : x;
            ls[i] = inside ? lad2 : 0.0f;
        }

#pragma unroll
        for (int i = 0; i < ROWS; ++i)
            __builtin_nontemporal_store(ys[i], &Y[(rb + i) * ND + fl]);

        // pure-VALU DPP reduce within 16-lane groups; lane 15 holds group sum
#pragma unroll
        for (int i = 0; i < ROWS; ++i) ls[i] = dpp_row_reduce16(ls[i]);
        if ((t & 15) == 15) {
            int g = fl >> 4;  // 0..31
#pragma unroll
            for (int i = 0; i < ROWS; ++i)
                sPart[it * 16 + hf * ROWS + i][g] = ls[i];
        }
        // no barrier: each sweep writes a distinct sPart region

#pragma unroll
        for (int i = 0; i < ROWS; ++i) xs[i] = xn[i];
    }

    // ---- epilogue: finish all 64 rows' logdet in one pass ----
    __syncthreads();
    {
        const int rl = t >> 4;              // local row 0..63
        const int c = t & 15;               // 16 threads per row
        const int it = rl >> 4;             // sweep
        const int rem = rl & 15;            // row within sweep (incl. half)
        float2 v2 = *(const float2*)&sPart[rl][c * 2];
        float v = v2.x + v2.y;
        v += __shfl_xor(v, 1, 16);
        v += __shfl_xor(v, 2, 16);
        v += __shfl_xor(v, 4, 16);
        v += __shfl_xor(v, 8, 16);
        if (c == 0) {
            const int row = blockIdx.x * 16 + it * (NBLK * 16) + rem;
            logdet[row] = v * 0.6931471805599453f;
        }
    }
}

extern "C" void kernel_launch(void* const* d_in, const int* in_sizes, int n_in,
                              void* d_out, int out_size, void* d_ws, size_t ws_size,
                              hipStream_t stream) {
    const float* x  = (const float*)d_in[0];
    const float* uw = (const float*)d_in[1];
    const float* uh = (const float*)d_in[2];
    const float* ud = (const float*)d_in[3];

    float* out = (float*)d_out;
    float* Y = out;                              // [NB*ND]
    float* logdet = out + (size_t)NB * ND;       // [NB]

    hipLaunchKernelGGL(rqs_all, dim3(NBLK), dim3(1024), 0, stream,
                       x, uw, uh, ud, Y, logdet);
}